// Round 8
// baseline (875.833 us; speedup 1.0000x reference)
//
#include <hip/hip_runtime.h>
#include <hip/hip_bf16.h>

using u16 = unsigned short;
using u32 = unsigned int;

typedef __bf16 bf16x8 __attribute__((ext_vector_type(8)));
typedef float  f32x4  __attribute__((ext_vector_type(4)));
typedef u32    u32x4  __attribute__((ext_vector_type(4)));
typedef u16    u16x8  __attribute__((ext_vector_type(8)));

__device__ __forceinline__ float bflo(u32 u){ union { u32 u; float f; } c; c.u = u << 16;          return c.f; }
__device__ __forceinline__ float bfhi(u32 u){ union { u32 u; float f; } c; c.u = u & 0xffff0000u;  return c.f; }
__device__ __forceinline__ u16  f2bf(float f){
  union { float f; u32 u; } c; c.f = f;
  u32 u = c.u;
  return (u16)((u + 0x7fffu + ((u >> 16) & 1u)) >> 16); // RNE
}

__device__ __forceinline__ void gload_lds16(const void* g, void* l){
  __builtin_amdgcn_global_load_lds(
      (const __attribute__((address_space(1))) void*)g,
      (__attribute__((address_space(3))) void*)l, 16, 0, 0);
}

// ---------------- prep: degree count, hierarchical scan (8-padded), CSR ----------------

__global__ void count_deg_kernel(const int* __restrict__ dst, int E, int* __restrict__ cnt){
  int i = blockIdx.x * blockDim.x + threadIdx.x;
  if (i < E) atomicAdd(&cnt[dst[i]], 1);
}

__global__ void scan1_kernel(const int* __restrict__ cnt, int n,
                             int* __restrict__ excl, int* __restrict__ bsums){
  __shared__ int sd[1024];
  const int tid = threadIdx.x;
  const int i = blockIdx.x * 1024 + tid;
  int v = 0;
  if (i < n){ v = (cnt[i] + 7) & ~7; if (v == 0) v = 8; }  // every list >= 1 chunk
  sd[tid] = v;
  __syncthreads();
  for (int s = 1; s < 1024; s <<= 1){
    int t = (tid >= s) ? sd[tid - s] : 0;
    __syncthreads();
    sd[tid] += t;
    __syncthreads();
  }
  if (i < n) excl[i] = sd[tid] - v;
  if (tid == 1023) bsums[blockIdx.x] = sd[tid];
}

__global__ void scan2_kernel(int* __restrict__ bsums, int nb){
  __shared__ int sd[256];
  const int tid = threadIdx.x;
  int v = (tid < nb) ? bsums[tid] : 0;
  sd[tid] = v;
  __syncthreads();
  for (int s = 1; s < 256; s <<= 1){
    int t = (tid >= s) ? sd[tid - s] : 0;
    __syncthreads();
    sd[tid] += t;
    __syncthreads();
  }
  if (tid < nb) bsums[tid] = sd[tid] - v;
  if (tid == nb - 1) bsums[nb] = sd[tid];
}

__global__ void finalize_kernel(int* __restrict__ rowptr, int* __restrict__ cursor,
                                const int* __restrict__ bsums, int nb,
                                const int* __restrict__ cnt,
                                float* __restrict__ dis, int n){
  int i = blockIdx.x * blockDim.x + threadIdx.x;
  if (i < n){
    int r = rowptr[i] + bsums[i >> 10];
    rowptr[i] = r;
    cursor[i] = r;
    dis[i] = rsqrtf((float)(cnt[i] + 1)); // +1 self loop
  }
  if (i == 0){
    rowptr[n] = bsums[nb];
    dis[n] = 0.f;                          // sentinel node
  }
}

__global__ void fill_csr_kernel(const int* __restrict__ src, const int* __restrict__ dst,
                                int E, int* __restrict__ cursor, u16* __restrict__ col){
  int i = blockIdx.x * blockDim.x + threadIdx.x;
  if (i < E){
    int d = dst[i];
    int p = atomicAdd(&cursor[d], 1);
    col[p] = (u16)src[i];
  }
}

__global__ void pad_fill_kernel(const int* __restrict__ rowptr, const int* __restrict__ cnt,
                                int N, u16* __restrict__ col){
  int v = blockIdx.x * blockDim.x + threadIdx.x;
  if (v < N){
    int p = rowptr[v] + cnt[v];
    const int p1 = rowptr[v + 1];
    for (; p < p1; ++p) col[p] = (u16)N;
  }
  if (v == 0){
    int t = rowptr[N];
    for (int j = 0; j < 32; ++j) col[t + j] = (u16)N;
  }
}

// xs[row] = bf16(dis[row] * x[row][:]) ; pad rows (incl. sentinel N) zero
__global__ void convert_x_kernel(const float* __restrict__ x, const float* __restrict__ dis,
                                 u32* __restrict__ xb, int n_real, int n_tot){
  int i8 = (blockIdx.x * blockDim.x + threadIdx.x) * 8;
  if (i8 >= n_tot) return;
  u32 q0, q1, q2, q3;
  if (i8 < n_real){
    const float dv = dis[i8 >> 9];
    const f32x4* xp = (const f32x4*)(x + i8);
    f32x4 a = xp[0], b = xp[1];
    q0 = ((u32)f2bf(dv * a[1]) << 16) | f2bf(dv * a[0]);
    q1 = ((u32)f2bf(dv * a[3]) << 16) | f2bf(dv * a[2]);
    q2 = ((u32)f2bf(dv * b[1]) << 16) | f2bf(dv * b[0]);
    q3 = ((u32)f2bf(dv * b[3]) << 16) | f2bf(dv * b[2]);
  } else {
    q0 = q1 = q2 = q3 = 0u;
  }
  u32x4 q = {q0, q1, q2, q3};
  *(u32x4*)(xb + (i8 >> 1)) = q;
}

// Wt[l][n][k] = bf16(W[l][k][n])
__global__ void convert_w_kernel(const float* __restrict__ W, u16* __restrict__ Wt, int total){
  int i = blockIdx.x * blockDim.x + threadIdx.x;
  if (i >= total) return;
  int k = i & 511, n = (i >> 9) & 511, l = i >> 18;
  Wt[i] = f2bf(W[(l << 18) | (k << 9) | n]);
}

// ---------------- per-node aggregation (round-6 pipeline) ----------------

#define GATHER8(p, c) \
  p##0 = ld((u32)(c)[0]); p##1 = ld((u32)(c)[1]); p##2 = ld((u32)(c)[2]); p##3 = ld((u32)(c)[3]); \
  p##4 = ld((u32)(c)[4]); p##5 = ld((u32)(c)[5]); p##6 = ld((u32)(c)[6]); p##7 = ld((u32)(c)[7]);

#define ACCQ(q) \
  a0 += bflo((q)[0]); a1 += bfhi((q)[0]); a2 += bflo((q)[1]); a3 += bfhi((q)[1]); \
  a4 += bflo((q)[2]); a5 += bfhi((q)[2]); a6 += bflo((q)[3]); a7 += bfhi((q)[3]);

#define CONS8(p) \
  ACCQ(p##0) ACCQ(p##1) ACCQ(p##2) ACCQ(p##3) ACCQ(p##4) ACCQ(p##5) ACCQ(p##6) ACCQ(p##7)

__device__ __forceinline__ void agg_node(int v, int lane, const char* __restrict__ xsb,
                                         const int* __restrict__ rowptr,
                                         const u16* __restrict__ col,
                                         const float* __restrict__ dis,
                                         u32* __restrict__ ob){
  const u32 loff = (u32)(lane << 4);
  auto ld = [&](u32 node) -> u32x4 {
    return *(const u32x4*)(xsb + (((size_t)node << 10) + loff));
  };

  float a0, a1, a2, a3, a4, a5, a6, a7;
  {
    u32x4 q = ld((u32)v);  // self loop term
    a0 = bflo(q[0]); a1 = bfhi(q[0]); a2 = bflo(q[1]); a3 = bfhi(q[1]);
    a4 = bflo(q[2]); a5 = bfhi(q[2]); a6 = bflo(q[3]); a7 = bfhi(q[3]);
  }

  const int e0 = rowptr[v];
  const int m  = (rowptr[v + 1] - e0) >> 3;   // >= 1
  const u16* cp = col + e0;

  u32x4 qa0, qa1, qa2, qa3, qa4, qa5, qa6, qa7;
  u32x4 qb0, qb1, qb2, qb3, qb4, qb5, qb6, qb7;

  u16x8 c0 = *(const u16x8*)cp;
  u16x8 c1 = *(const u16x8*)(cp + 8);     // over-read -> sentinel slack
  GATHER8(qa, c0);

  int i = 1;
  for (; i + 1 < m; i += 2){
    c0 = *(const u16x8*)(cp + 8 * (i + 1));
    GATHER8(qb, c1);
    CONS8(qa);
    c1 = *(const u16x8*)(cp + 8 * (i + 2));
    GATHER8(qa, c0);
    CONS8(qb);
  }
  if (i < m){
    GATHER8(qb, c1);
    CONS8(qa);
    CONS8(qb);
  } else {
    CONS8(qa);
  }

  const float dv = dis[v];
  u32x4 r;
  r[0] = ((u32)f2bf(dv * a1) << 16) | f2bf(dv * a0);
  r[1] = ((u32)f2bf(dv * a3) << 16) | f2bf(dv * a2);
  r[2] = ((u32)f2bf(dv * a5) << 16) | f2bf(dv * a4);
  r[3] = ((u32)f2bf(dv * a7) << 16) | f2bf(dv * a6);
  *(u32x4*)(ob + (((size_t)v) << 8) + (lane << 2)) = r;
}

// ---------------- fused layer: persistent blocks, queue = [782 agg bands | 1564 gemm tiles] ----
// agg band i: nodes [i*64, i*64+64): read xsb -> write aggb; release-store flags[i]=1.
// gemm tile t: band=t>>2 (rows band*128 of aggb), bn=(t&3)*128; spins on flags[2b],[2b+1];
// writes xs_out (NOT xsb -- triple-buffered to avoid racing in-flight agg reads).
// Deadlock-free: gemm items are claimed only after ALL agg items are claimed, and every
// claimed agg item is executed to completion by a resident, never-blocking block.

__global__ __launch_bounds__(256) void layer_kernel(const char* __restrict__ xsb,
                                                    const int* __restrict__ rowptr,
                                                    const u16* __restrict__ col,
                                                    const float* __restrict__ dis,
                                                    u32* __restrict__ aggb_u32,
                                                    const u16* __restrict__ Bt,
                                                    const float* __restrict__ bias,
                                                    u16* __restrict__ Cb,
                                                    float* __restrict__ Cf,
                                                    int* __restrict__ flags,
                                                    int* __restrict__ queue,
                                                    int n_agg, int n_items,
                                                    int N, int last){
  __shared__ u16 sA[2][128 * 64];
  __shared__ u16 sB[2][128 * 64];
  __shared__ int s_item;

  const int tid  = threadIdx.x;
  const int lane = tid & 63;
  const int wv   = tid >> 6;

  for (;;){
    __syncthreads();
    if (tid == 0) s_item = atomicAdd(queue, 1);
    __syncthreads();
    const int item = s_item;
    if (item >= n_items) return;

    if (item < n_agg){
      // ---- aggregation band: 64 nodes, 16 per wave ----
      const int base = item * 64 + wv * 16;
      for (int j = 0; j < 16; ++j){
        const int v = base + j;
        if (v < N) agg_node(v, lane, xsb, rowptr, col, dis, aggb_u32);
      }
      __syncthreads();
      if (tid == 0){
        __threadfence();
        __hip_atomic_store(&flags[item], 1, __ATOMIC_RELEASE, __HIP_MEMORY_SCOPE_AGENT);
      }
    } else {
      // ---- GEMM tile ----
      const int t    = item - n_agg;
      const int band = t >> 2;
      const int bm0  = band * 128;
      const int bn0  = (t & 3) * 128;
      if (tid == 0){
        while (__hip_atomic_load(&flags[2 * band],     __ATOMIC_ACQUIRE, __HIP_MEMORY_SCOPE_AGENT) == 0)
          __builtin_amdgcn_s_sleep(8);
        while (__hip_atomic_load(&flags[2 * band + 1], __ATOMIC_ACQUIRE, __HIP_MEMORY_SCOPE_AGENT) == 0)
          __builtin_amdgcn_s_sleep(8);
      }
      __syncthreads();

      const u16* A = (const u16*)aggb_u32;
      const int wm = wv >> 1, wn = wv & 1;
      const int sr = lane >> 3;
      const int sc = (lane & 7) << 3;

      f32x4 acc[4][4] = {};

      auto stage = [&](int bsel, int tt){
        const int k0 = tt * 64;
        #pragma unroll
        for (int i = 0; i < 4; ++i){
          const int rr = ((wv * 4 + i) << 3) + sr;
          gload_lds16(A  + (((size_t)(bm0 + rr)) << 9) + k0 + sc, (void*)&sA[bsel][(wv * 4 + i) * 512]);
          gload_lds16(Bt + (((size_t)(bn0 + rr)) << 9) + k0 + sc, (void*)&sB[bsel][(wv * 4 + i) * 512]);
        }
      };

      stage(0, 0);
      __syncthreads();
      int cur = 0;
      const int lr = lane & 15, lg = lane >> 4;

      for (int tt = 0; tt < 8; ++tt){
        if (tt < 7) stage(cur ^ 1, tt + 1);
        const bf16x8* A8 = (const bf16x8*)sA[cur];
        const bf16x8* B8 = (const bf16x8*)sB[cur];
        #pragma unroll
        for (int ks = 0; ks < 2; ++ks){
          bf16x8 af[4], bg[4];
          #pragma unroll
          for (int mi = 0; mi < 4; ++mi)
            af[mi] = A8[((wm * 64 + mi * 16 + lr) << 3) + (ks << 2) + lg];
          #pragma unroll
          for (int ni = 0; ni < 4; ++ni)
            bg[ni] = B8[((wn * 64 + ni * 16 + lr) << 3) + (ks << 2) + lg];
          #pragma unroll
          for (int mi = 0; mi < 4; ++mi)
            #pragma unroll
            for (int ni = 0; ni < 4; ++ni)
              acc[mi][ni] = __builtin_amdgcn_mfma_f32_16x16x32_bf16(af[mi], bg[ni], acc[mi][ni], 0, 0, 0);
        }
        __syncthreads();
        cur ^= 1;
      }

      float bb[4];
      #pragma unroll
      for (int ni = 0; ni < 4; ++ni) bb[ni] = bias[bn0 + wn * 64 + ni * 16 + lr];

      // C/D layout: col=lane&15, row=(lane>>4)*4+reg  [m89-verified]
      #pragma unroll
      for (int mi = 0; mi < 4; ++mi){
        const int row0 = bm0 + wm * 64 + mi * 16 + (lg << 2);
        #pragma unroll
        for (int ni = 0; ni < 4; ++ni){
          const int c0 = bn0 + wn * 64 + ni * 16 + lr;
          #pragma unroll
          for (int r = 0; r < 4; ++r){
            const int row = row0 + r;
            const float val = fmaxf(acc[mi][ni][r] + bb[ni], 0.f);
            if (!last){
              Cb[(((size_t)row) << 9) + c0] = (row < N) ? f2bf(dis[row] * val) : (u16)0;
            } else if (row < N){
              Cf[(((size_t)row) << 9) + c0] = val;
            }
          }
        }
      }
    }
  }
}

// ---------------- launch ----------------

extern "C" void kernel_launch(void* const* d_in, const int* in_sizes, int n_in,
                              void* d_out, int out_size, void* d_ws, size_t ws_size,
                              hipStream_t stream) {
  const float* x    = (const float*)d_in[0];
  const int*   ei   = (const int*)d_in[1];   // [2][E] int32: src = ei, dst = ei + E
  const float* W    = (const float*)d_in[2]; // [L][512][512]
  const float* bias = (const float*)d_in[3]; // [L][512]
  float* out = (float*)d_out;

  const int N = in_sizes[0] >> 9;       // 50000
  const int E = in_sizes[1] >> 1;       // 800000
  const int L = in_sizes[3] >> 9;       // 3
  const int MPAD = (N + 127) & ~127;    // 50048 (> N, so row N is a zero pad row)
  const int NB = (N + 1023) / 1024;     // scan blocks (49)
  const int NAGG  = MPAD / 64;          // 782 agg bands
  const int NGEMM = (MPAD / 128) * 4;   // 1564 gemm tiles
  const int NITEMS = NAGG + NGEMM;
  const int CTRL = NAGG + 1;            // per-layer control ints: flags[NAGG] + queue

  char* p = (char*)d_ws;
  auto alloc = [&](size_t bytes){ char* q = p; p += (bytes + 255) & ~(size_t)255; return q; };
  u16*   xb       = (u16*)alloc((size_t)MPAD * 512 * 2);
  u16*   xb2      = (u16*)alloc((size_t)MPAD * 512 * 2);   // ping-pong xs buffer
  u16*   aggb     = (u16*)alloc((size_t)MPAD * 512 * 2);
  u16*   wt       = (u16*)alloc((size_t)L * 512 * 512 * 2);
  float* dis      = (float*)alloc((size_t)(N + 1) * 4);
  int*   rowptr_d = (int*)alloc((size_t)(N + 1) * 4);
  int*   cursor_d = (int*)alloc((size_t)N * 4);
  int*   cnt_d    = (int*)alloc((size_t)N * 4);
  u16*   col      = (u16*)alloc(((size_t)E + 8 * (size_t)N + 64) * 2);
  int*   bsums_d  = (int*)alloc(256 * 4);
  int*   ctrl     = (int*)alloc((size_t)L * CTRL * 4);

  hipMemsetAsync(cnt_d, 0, (size_t)N * 4, stream);
  hipMemsetAsync(ctrl, 0, (size_t)L * CTRL * 4, stream);
  // zero pad rows of aggb once per call; agg only writes rows < N.
  // (xb pad rows zeroed by convert_x; xb2 rows are ALL written by layer-0 GEMM.)
  hipMemsetAsync(aggb + (size_t)N * 512, 0, (size_t)(MPAD - N) * 512 * 2, stream);

  count_deg_kernel<<<(E + 255) / 256, 256, 0, stream>>>(ei + E, E, cnt_d);
  scan1_kernel<<<NB, 1024, 0, stream>>>(cnt_d, N, rowptr_d, bsums_d);
  scan2_kernel<<<1, 256, 0, stream>>>(bsums_d, NB);
  finalize_kernel<<<(N + 255) / 256, 256, 0, stream>>>(rowptr_d, cursor_d, bsums_d, NB, cnt_d, dis, N);
  fill_csr_kernel<<<(E + 255) / 256, 256, 0, stream>>>(ei, ei + E, E, cursor_d, col);
  pad_fill_kernel<<<(N + 255) / 256, 256, 0, stream>>>(rowptr_d, cnt_d, N, col);

  const int ntot = MPAD * 512;
  convert_x_kernel<<<(ntot / 8 + 255) / 256, 256, 0, stream>>>(x, dis, (u32*)xb, N * 512, ntot);
  convert_w_kernel<<<(L * 512 * 512 + 255) / 256, 256, 0, stream>>>(W, wt, L * 512 * 512);

  for (int l = 0; l < L; ++l){
    int* fl = ctrl + (size_t)l * CTRL;
    const u16* xs_in  = (l & 1) ? xb2 : xb;
    u16*       xs_out = (l & 1) ? xb  : xb2;
    layer_kernel<<<512, 256, 0, stream>>>((const char*)xs_in, rowptr_d, col, dis,
                                          (u32*)aggb,
                                          wt + (size_t)l * 512 * 512,
                                          bias + (size_t)l * 512,
                                          xs_out, out,
                                          fl, fl + NAGG,
                                          NAGG, NITEMS, N, (l == L - 1) ? 1 : 0);
  }
}

// Round 9
// 680.155 us; speedup vs baseline: 1.2877x; 1.2877x over previous
//
#include <hip/hip_runtime.h>
#include <hip/hip_bf16.h>

using u16 = unsigned short;
using u32 = unsigned int;

typedef __bf16 bf16x8 __attribute__((ext_vector_type(8)));
typedef float  f32x4  __attribute__((ext_vector_type(4)));
typedef u32    u32x4  __attribute__((ext_vector_type(4)));
typedef u16    u16x8  __attribute__((ext_vector_type(8)));

__device__ __forceinline__ float bflo(u32 u){ union { u32 u; float f; } c; c.u = u << 16;          return c.f; }
__device__ __forceinline__ float bfhi(u32 u){ union { u32 u; float f; } c; c.u = u & 0xffff0000u;  return c.f; }
__device__ __forceinline__ u16  f2bf(float f){
  union { float f; u32 u; } c; c.f = f;
  u32 u = c.u;
  return (u16)((u + 0x7fffu + ((u >> 16) & 1u)) >> 16); // RNE
}

__device__ __forceinline__ void gload_lds16(const void* g, void* l){
  __builtin_amdgcn_global_load_lds(
      (const __attribute__((address_space(1))) void*)g,
      (__attribute__((address_space(3))) void*)l, 16, 0, 0);
}

// ---------------- prep: degree count, hierarchical scan (8-padded), CSR ----------------

__global__ void count_deg_kernel(const int* __restrict__ dst, int E, int* __restrict__ cnt){
  int i = blockIdx.x * blockDim.x + threadIdx.x;
  if (i < E) atomicAdd(&cnt[dst[i]], 1);
}

__global__ void scan1_kernel(const int* __restrict__ cnt, int n,
                             int* __restrict__ excl, int* __restrict__ bsums){
  __shared__ int sd[1024];
  const int tid = threadIdx.x;
  const int i = blockIdx.x * 1024 + tid;
  int v = 0;
  if (i < n){ v = (cnt[i] + 7) & ~7; if (v == 0) v = 8; }  // every list >= 1 chunk
  sd[tid] = v;
  __syncthreads();
  for (int s = 1; s < 1024; s <<= 1){
    int t = (tid >= s) ? sd[tid - s] : 0;
    __syncthreads();
    sd[tid] += t;
    __syncthreads();
  }
  if (i < n) excl[i] = sd[tid] - v;
  if (tid == 1023) bsums[blockIdx.x] = sd[tid];
}

__global__ void scan2_kernel(int* __restrict__ bsums, int nb){
  __shared__ int sd[256];
  const int tid = threadIdx.x;
  int v = (tid < nb) ? bsums[tid] : 0;
  sd[tid] = v;
  __syncthreads();
  for (int s = 1; s < 256; s <<= 1){
    int t = (tid >= s) ? sd[tid - s] : 0;
    __syncthreads();
    sd[tid] += t;
    __syncthreads();
  }
  if (tid < nb) bsums[tid] = sd[tid] - v;
  if (tid == nb - 1) bsums[nb] = sd[tid];
}

__global__ void finalize_kernel(int* __restrict__ rowptr, int* __restrict__ cursor,
                                const int* __restrict__ bsums, int nb,
                                const int* __restrict__ cnt,
                                float* __restrict__ dis, int n){
  int i = blockIdx.x * blockDim.x + threadIdx.x;
  if (i < n){
    int r = rowptr[i] + bsums[i >> 10];
    rowptr[i] = r;
    cursor[i] = r;
    dis[i] = rsqrtf((float)(cnt[i] + 1)); // +1 self loop
  }
  if (i == 0){
    rowptr[n] = bsums[nb];
    dis[n] = 0.f;                          // sentinel node
  }
}

__global__ void fill_csr_kernel(const int* __restrict__ src, const int* __restrict__ dst,
                                int E, int* __restrict__ cursor, u16* __restrict__ col){
  int i = blockIdx.x * blockDim.x + threadIdx.x;
  if (i < E){
    int d = dst[i];
    int p = atomicAdd(&cursor[d], 1);
    col[p] = (u16)src[i];
  }
}

__global__ void pad_fill_kernel(const int* __restrict__ rowptr, const int* __restrict__ cnt,
                                int N, u16* __restrict__ col){
  int v = blockIdx.x * blockDim.x + threadIdx.x;
  if (v < N){
    int p = rowptr[v] + cnt[v];
    const int p1 = rowptr[v + 1];
    for (; p < p1; ++p) col[p] = (u16)N;
  }
  if (v == 0){
    int t = rowptr[N];
    for (int j = 0; j < 32; ++j) col[t + j] = (u16)N;
  }
}

// xs[row] = bf16(dis[row] * x[row][:]) ; pad rows (incl. sentinel N) zero
__global__ void convert_x_kernel(const float* __restrict__ x, const float* __restrict__ dis,
                                 u32* __restrict__ xb, int n_real, int n_tot){
  int i8 = (blockIdx.x * blockDim.x + threadIdx.x) * 8;
  if (i8 >= n_tot) return;
  u32 q0, q1, q2, q3;
  if (i8 < n_real){
    const float dv = dis[i8 >> 9];
    const f32x4* xp = (const f32x4*)(x + i8);
    f32x4 a = xp[0], b = xp[1];
    q0 = ((u32)f2bf(dv * a[1]) << 16) | f2bf(dv * a[0]);
    q1 = ((u32)f2bf(dv * a[3]) << 16) | f2bf(dv * a[2]);
    q2 = ((u32)f2bf(dv * b[1]) << 16) | f2bf(dv * b[0]);
    q3 = ((u32)f2bf(dv * b[3]) << 16) | f2bf(dv * b[2]);
  } else {
    q0 = q1 = q2 = q3 = 0u;
  }
  u32x4 q = {q0, q1, q2, q3};
  *(u32x4*)(xb + (i8 >> 1)) = q;
}

// Wt[l][n][k] = bf16(W[l][k][n])
__global__ void convert_w_kernel(const float* __restrict__ W, u16* __restrict__ Wt, int total){
  int i = blockIdx.x * blockDim.x + threadIdx.x;
  if (i >= total) return;
  int k = i & 511, n = (i >> 9) & 511, l = i >> 18;
  Wt[i] = f2bf(W[(l << 18) | (k << 9) | n]);
}

// ---------------- aggregation: one wave per node, 8-wide chunks, col 2-ahead ----------------
// agg[v] = dis[v] * ( xs[v] + sum_s xs[s] )   (xs bf16, f32 accum)
// lists padded to multiples of 8 (>=8) with sentinel N (xs[N]=0).

#define GATHER8(p, c) \
  p##0 = ld((u32)(c)[0]); p##1 = ld((u32)(c)[1]); p##2 = ld((u32)(c)[2]); p##3 = ld((u32)(c)[3]); \
  p##4 = ld((u32)(c)[4]); p##5 = ld((u32)(c)[5]); p##6 = ld((u32)(c)[6]); p##7 = ld((u32)(c)[7]);

#define ACCQ(q) \
  a0 += bflo((q)[0]); a1 += bfhi((q)[0]); a2 += bflo((q)[1]); a3 += bfhi((q)[1]); \
  a4 += bflo((q)[2]); a5 += bfhi((q)[2]); a6 += bflo((q)[3]); a7 += bfhi((q)[3]);

#define CONS8(p) \
  ACCQ(p##0) ACCQ(p##1) ACCQ(p##2) ACCQ(p##3) ACCQ(p##4) ACCQ(p##5) ACCQ(p##6) ACCQ(p##7)

__global__ __launch_bounds__(256) void aggregate_kernel(const char* __restrict__ xsb,
                                                        const int* __restrict__ rowptr,
                                                        const u16* __restrict__ col,
                                                        const float* __restrict__ dis,
                                                        u32* __restrict__ ob, int N){
  const int lane = threadIdx.x & 63;
  const int v = blockIdx.x * 4 + (threadIdx.x >> 6);
  if (v >= N) return;
  const u32 loff = (u32)(lane << 4);

  auto ld = [&](u32 node) -> u32x4 {
    return *(const u32x4*)(xsb + (((size_t)node << 10) + loff));
  };

  float a0, a1, a2, a3, a4, a5, a6, a7;
  {
    u32x4 q = ld((u32)v);  // self loop term
    a0 = bflo(q[0]); a1 = bfhi(q[0]); a2 = bflo(q[1]); a3 = bfhi(q[1]);
    a4 = bflo(q[2]); a5 = bfhi(q[2]); a6 = bflo(q[3]); a7 = bfhi(q[3]);
  }

  const int e0 = rowptr[v];
  const int m  = (rowptr[v + 1] - e0) >> 3;   // >= 1
  const u16* cp = col + e0;

  u32x4 qa0, qa1, qa2, qa3, qa4, qa5, qa6, qa7;
  u32x4 qb0, qb1, qb2, qb3, qb4, qb5, qb6, qb7;

  u16x8 c0 = *(const u16x8*)cp;
  u16x8 c1 = *(const u16x8*)(cp + 8);     // over-read -> sentinel slack
  GATHER8(qa, c0);

  int i = 1;
  for (; i + 1 < m; i += 2){
    c0 = *(const u16x8*)(cp + 8 * (i + 1));
    GATHER8(qb, c1);
    CONS8(qa);
    c1 = *(const u16x8*)(cp + 8 * (i + 2));
    GATHER8(qa, c0);
    CONS8(qb);
  }
  if (i < m){
    GATHER8(qb, c1);
    CONS8(qa);
    CONS8(qb);
  } else {
    CONS8(qa);
  }

  const float dv = dis[v];
  u32x4 r;
  r[0] = ((u32)f2bf(dv * a1) << 16) | f2bf(dv * a0);
  r[1] = ((u32)f2bf(dv * a3) << 16) | f2bf(dv * a2);
  r[2] = ((u32)f2bf(dv * a5) << 16) | f2bf(dv * a4);
  r[3] = ((u32)f2bf(dv * a7) << 16) | f2bf(dv * a6);
  *(u32x4*)(ob + (((size_t)v) << 8) + (lane << 2)) = r;
}

// ---------------- GEMM: C = relu(A * W + b); non-last: Cb = bf16(dis*C); last: f32 out ----
// 128x128 tile, BK=64, 4 waves (2x2), double-buffered gload_lds.
// LDS bank-conflict fix [rule #21]: linear LDS dest (gload_lds requirement) +
// pre-swizzled GLOBAL source chunk c^(row&7) + matching XOR on ds_read chunk index.
// Eliminates the 16-way conflict of the 128B-stride row-major tile (r8: 9.6M conflicts).

__global__ __launch_bounds__(256) void gemm_kernel(const u16* __restrict__ A,
                                                   const u16* __restrict__ Bt,
                                                   const float* __restrict__ bias,
                                                   const float* __restrict__ dis,
                                                   u16* __restrict__ Cb,
                                                   float* __restrict__ Cf,
                                                   int n_real, int last){
  __shared__ u16 sA[2][128 * 64];
  __shared__ u16 sB[2][128 * 64];

  // bijective XCD-chunk swizzle (m204)
  const int nwg  = gridDim.x;
  const int q8   = nwg >> 3, r8 = nwg & 7;
  const int xcd  = blockIdx.x & 7, oi = blockIdx.x >> 3;
  const int wg   = ((xcd < r8) ? xcd * (q8 + 1) : r8 * (q8 + 1) + (xcd - r8) * q8) + oi;
  const int bm0  = (wg >> 2) * 128;
  const int bn0  = (wg & 3) * 128;

  const int tid  = threadIdx.x;
  const int lane = tid & 63;
  const int wv   = tid >> 6;
  const int wm   = wv >> 1, wn = wv & 1;
  const int sr   = lane >> 3;                         // row within 8-row stage group
  const int sc   = (((lane & 7) ^ sr) << 3);          // PRE-SWIZZLED global k-chunk

  f32x4 acc[4][4] = {};

  auto stage = [&](int bsel, int t){
    const int k0 = t * 64;
    #pragma unroll
    for (int i = 0; i < 4; ++i){
      const int rr = ((wv * 4 + i) << 3) + sr;
      gload_lds16(A  + (((size_t)(bm0 + rr)) << 9) + k0 + sc, (void*)&sA[bsel][(wv * 4 + i) * 512]);
      gload_lds16(Bt + (((size_t)(bn0 + rr)) << 9) + k0 + sc, (void*)&sB[bsel][(wv * 4 + i) * 512]);
    }
  };

  stage(0, 0);
  __syncthreads();
  int cur = 0;
  const int lr = lane & 15, lg = lane >> 4;
  const int x7 = lr & 7;                              // read-side swizzle key

  for (int t = 0; t < 8; ++t){
    if (t < 7) stage(cur ^ 1, t + 1);
    const bf16x8* A8 = (const bf16x8*)sA[cur];
    const bf16x8* B8 = (const bf16x8*)sB[cur];
    #pragma unroll
    for (int ks = 0; ks < 2; ++ks){
      const int cswz = ((ks << 2) + lg) ^ x7;         // swizzled 16B-chunk index
      bf16x8 af[4], bg[4];
      #pragma unroll
      for (int mi = 0; mi < 4; ++mi)
        af[mi] = A8[((wm * 64 + mi * 16 + lr) << 3) + cswz];
      #pragma unroll
      for (int ni = 0; ni < 4; ++ni)
        bg[ni] = B8[((wn * 64 + ni * 16 + lr) << 3) + cswz];
      #pragma unroll
      for (int mi = 0; mi < 4; ++mi)
        #pragma unroll
        for (int ni = 0; ni < 4; ++ni)
          acc[mi][ni] = __builtin_amdgcn_mfma_f32_16x16x32_bf16(af[mi], bg[ni], acc[mi][ni], 0, 0, 0);
    }
    __syncthreads();
    cur ^= 1;
  }

  float bb[4];
  #pragma unroll
  for (int ni = 0; ni < 4; ++ni) bb[ni] = bias[bn0 + wn * 64 + ni * 16 + lr];

  // C/D layout: col=lane&15, row=(lane>>4)*4+reg  [m89-verified]
  #pragma unroll
  for (int mi = 0; mi < 4; ++mi){
    const int row0 = bm0 + wm * 64 + mi * 16 + (lg << 2);
    const f32x4 dv4 = *(const f32x4*)(dis + row0);   // dis padded to MPAD+4; >=N lanes discarded
    #pragma unroll
    for (int ni = 0; ni < 4; ++ni){
      const int c0 = bn0 + wn * 64 + ni * 16 + lr;
      #pragma unroll
      for (int r = 0; r < 4; ++r){
        const int row = row0 + r;
        const float val = fmaxf(acc[mi][ni][r] + bb[ni], 0.f);
        if (!last){
          Cb[(((size_t)row) << 9) + c0] = (row < n_real) ? f2bf(dv4[r] * val) : (u16)0;
        } else if (row < n_real){
          Cf[(((size_t)row) << 9) + c0] = val;
        }
      }
    }
  }
}

// ---------------- launch ----------------

extern "C" void kernel_launch(void* const* d_in, const int* in_sizes, int n_in,
                              void* d_out, int out_size, void* d_ws, size_t ws_size,
                              hipStream_t stream) {
  const float* x    = (const float*)d_in[0];
  const int*   ei   = (const int*)d_in[1];   // [2][E] int32: src = ei, dst = ei + E
  const float* W    = (const float*)d_in[2]; // [L][512][512]
  const float* bias = (const float*)d_in[3]; // [L][512]
  float* out = (float*)d_out;

  const int N = in_sizes[0] >> 9;       // 50000
  const int E = in_sizes[1] >> 1;       // 800000
  const int L = in_sizes[3] >> 9;       // 3
  const int MPAD = (N + 127) & ~127;    // 50048 (> N, so row N is a zero pad row)
  const int NB = (N + 1023) / 1024;     // scan blocks (49)

  char* p = (char*)d_ws;
  auto alloc = [&](size_t bytes){ char* q = p; p += (bytes + 255) & ~(size_t)255; return q; };
  u16*   xb       = (u16*)alloc((size_t)MPAD * 512 * 2);
  u16*   aggb     = (u16*)alloc((size_t)MPAD * 512 * 2);
  u16*   wt       = (u16*)alloc((size_t)L * 512 * 512 * 2);
  float* dis      = (float*)alloc((size_t)(MPAD + 4) * 4);  // padded so epilogue f32x4 stays in-bounds
  int*   rowptr_d = (int*)alloc((size_t)(N + 1) * 4);
  int*   cursor_d = (int*)alloc((size_t)N * 4);
  int*   cnt_d    = (int*)alloc((size_t)N * 4);
  u16*   col      = (u16*)alloc(((size_t)E + 8 * (size_t)N + 64) * 2);
  int*   bsums_d  = (int*)alloc(256 * 4);

  hipMemsetAsync(cnt_d, 0, (size_t)N * 4, stream);
  // zero pad rows of aggb once per call; agg only writes rows < N
  hipMemsetAsync(aggb + (size_t)N * 512, 0, (size_t)(MPAD - N) * 512 * 2, stream);

  count_deg_kernel<<<(E + 255) / 256, 256, 0, stream>>>(ei + E, E, cnt_d);
  scan1_kernel<<<NB, 1024, 0, stream>>>(cnt_d, N, rowptr_d, bsums_d);
  scan2_kernel<<<1, 256, 0, stream>>>(bsums_d, NB);
  finalize_kernel<<<(N + 255) / 256, 256, 0, stream>>>(rowptr_d, cursor_d, bsums_d, NB, cnt_d, dis, N);
  fill_csr_kernel<<<(E + 255) / 256, 256, 0, stream>>>(ei, ei + E, E, cursor_d, col);
  pad_fill_kernel<<<(N + 255) / 256, 256, 0, stream>>>(rowptr_d, cnt_d, N, col);

  const int ntot = MPAD * 512;
  convert_x_kernel<<<(ntot / 8 + 255) / 256, 256, 0, stream>>>(x, dis, (u32*)xb, N * 512, ntot);
  convert_w_kernel<<<(L * 512 * 512 + 255) / 256, 256, 0, stream>>>(W, wt, L * 512 * 512);

  for (int l = 0; l < L; ++l){
    aggregate_kernel<<<(N + 3) / 4, 256, 0, stream>>>((const char*)xb, rowptr_d, col, dis,
                                                      (u32*)aggb, N);
    gemm_kernel<<<(MPAD / 128) * 4, 256, 0, stream>>>(aggb, wt + (size_t)l * 512 * 512,
                                                      bias + (size_t)l * 512, dis,
                                                      xb, out, N, (l == L - 1) ? 1 : 0);
  }
}

// Round 10
// 666.428 us; speedup vs baseline: 1.3142x; 1.0206x over previous
//
#include <hip/hip_runtime.h>
#include <hip/hip_bf16.h>

using u16 = unsigned short;
using u32 = unsigned int;

typedef __bf16 bf16x8 __attribute__((ext_vector_type(8)));
typedef float  f32x4  __attribute__((ext_vector_type(4)));
typedef u32    u32x4  __attribute__((ext_vector_type(4)));
typedef u16    u16x8  __attribute__((ext_vector_type(8)));

__device__ __forceinline__ float bflo(u32 u){ union { u32 u; float f; } c; c.u = u << 16;          return c.f; }
__device__ __forceinline__ float bfhi(u32 u){ union { u32 u; float f; } c; c.u = u & 0xffff0000u;  return c.f; }
__device__ __forceinline__ u16  f2bf(float f){
  union { float f; u32 u; } c; c.f = f;
  u32 u = c.u;
  return (u16)((u + 0x7fffu + ((u >> 16) & 1u)) >> 16); // RNE
}

__device__ __forceinline__ void gload_lds16(const void* g, void* l){
  __builtin_amdgcn_global_load_lds(
      (const __attribute__((address_space(1))) void*)g,
      (__attribute__((address_space(3))) void*)l, 16, 0, 0);
}

// ---------------- prep: degree count, hierarchical scan (8-padded), CSR ----------------

__global__ void count_deg_kernel(const int* __restrict__ dst, int E, int* __restrict__ cnt){
  int i = blockIdx.x * blockDim.x + threadIdx.x;
  if (i < E) atomicAdd(&cnt[dst[i]], 1);
}

__global__ void scan1_kernel(const int* __restrict__ cnt, int n,
                             int* __restrict__ excl, int* __restrict__ bsums){
  __shared__ int sd[1024];
  const int tid = threadIdx.x;
  const int i = blockIdx.x * 1024 + tid;
  int v = 0;
  if (i < n){ v = (cnt[i] + 7) & ~7; if (v == 0) v = 8; }  // every list >= 1 chunk
  sd[tid] = v;
  __syncthreads();
  for (int s = 1; s < 1024; s <<= 1){
    int t = (tid >= s) ? sd[tid - s] : 0;
    __syncthreads();
    sd[tid] += t;
    __syncthreads();
  }
  if (i < n) excl[i] = sd[tid] - v;
  if (tid == 1023) bsums[blockIdx.x] = sd[tid];
}

__global__ void scan2_kernel(int* __restrict__ bsums, int nb){
  __shared__ int sd[256];
  const int tid = threadIdx.x;
  int v = (tid < nb) ? bsums[tid] : 0;
  sd[tid] = v;
  __syncthreads();
  for (int s = 1; s < 256; s <<= 1){
    int t = (tid >= s) ? sd[tid - s] : 0;
    __syncthreads();
    sd[tid] += t;
    __syncthreads();
  }
  if (tid < nb) bsums[tid] = sd[tid] - v;
  if (tid == nb - 1) bsums[nb] = sd[tid];
}

__global__ void finalize_kernel(int* __restrict__ rowptr, int* __restrict__ cursor,
                                const int* __restrict__ bsums, int nb,
                                const int* __restrict__ cnt,
                                float* __restrict__ dis, int n){
  int i = blockIdx.x * blockDim.x + threadIdx.x;
  if (i < n){
    int r = rowptr[i] + bsums[i >> 10];
    rowptr[i] = r;
    cursor[i] = r;
    dis[i] = rsqrtf((float)(cnt[i] + 1)); // +1 self loop
  }
  if (i == 0){
    rowptr[n] = bsums[nb];
    dis[n] = 0.f;                          // sentinel node
  }
}

__global__ void fill_csr_kernel(const int* __restrict__ src, const int* __restrict__ dst,
                                int E, int* __restrict__ cursor, u16* __restrict__ col){
  int i = blockIdx.x * blockDim.x + threadIdx.x;
  if (i < E){
    int d = dst[i];
    int p = atomicAdd(&cursor[d], 1);
    col[p] = (u16)src[i];
  }
}

__global__ void pad_fill_kernel(const int* __restrict__ rowptr, const int* __restrict__ cnt,
                                int N, u16* __restrict__ col){
  int v = blockIdx.x * blockDim.x + threadIdx.x;
  if (v < N){
    int p = rowptr[v] + cnt[v];
    const int p1 = rowptr[v + 1];
    for (; p < p1; ++p) col[p] = (u16)N;
  }
  if (v == 0){
    int t = rowptr[N];
    for (int j = 0; j < 32; ++j) col[t + j] = (u16)N;
  }
}

// xs[row] = bf16(dis[row] * x[row][:]) ; pad rows (incl. sentinel N) zero
__global__ void convert_x_kernel(const float* __restrict__ x, const float* __restrict__ dis,
                                 u32* __restrict__ xb, int n_real, int n_tot){
  int i8 = (blockIdx.x * blockDim.x + threadIdx.x) * 8;
  if (i8 >= n_tot) return;
  u32 q0, q1, q2, q3;
  if (i8 < n_real){
    const float dv = dis[i8 >> 9];
    const f32x4* xp = (const f32x4*)(x + i8);
    f32x4 a = xp[0], b = xp[1];
    q0 = ((u32)f2bf(dv * a[1]) << 16) | f2bf(dv * a[0]);
    q1 = ((u32)f2bf(dv * a[3]) << 16) | f2bf(dv * a[2]);
    q2 = ((u32)f2bf(dv * b[1]) << 16) | f2bf(dv * b[0]);
    q3 = ((u32)f2bf(dv * b[3]) << 16) | f2bf(dv * b[2]);
  } else {
    q0 = q1 = q2 = q3 = 0u;
  }
  u32x4 q = {q0, q1, q2, q3};
  *(u32x4*)(xb + (i8 >> 1)) = q;
}

// Wt[l][n][k] = bf16(W[l][k][n])
__global__ void convert_w_kernel(const float* __restrict__ W, u16* __restrict__ Wt, int total){
  int i = blockIdx.x * blockDim.x + threadIdx.x;
  if (i >= total) return;
  int k = i & 511, n = (i >> 9) & 511, l = i >> 18;
  Wt[i] = f2bf(W[(l << 18) | (k << 9) | n]);
}

// ---------------- aggregation: one wave per node, 8-wide chunks, col 2-ahead ----------------
// agg[v] = dis[v] * ( xs[v] + sum_s xs[s] )   (xs bf16, f32 accum)
// lists padded to multiples of 8 (>=8) with sentinel N (xs[N]=0).

#define GATHER8(p, c) \
  p##0 = ld((u32)(c)[0]); p##1 = ld((u32)(c)[1]); p##2 = ld((u32)(c)[2]); p##3 = ld((u32)(c)[3]); \
  p##4 = ld((u32)(c)[4]); p##5 = ld((u32)(c)[5]); p##6 = ld((u32)(c)[6]); p##7 = ld((u32)(c)[7]);

#define ACCQ(q) \
  a0 += bflo((q)[0]); a1 += bfhi((q)[0]); a2 += bflo((q)[1]); a3 += bfhi((q)[1]); \
  a4 += bflo((q)[2]); a5 += bfhi((q)[2]); a6 += bflo((q)[3]); a7 += bfhi((q)[3]);

#define CONS8(p) \
  ACCQ(p##0) ACCQ(p##1) ACCQ(p##2) ACCQ(p##3) ACCQ(p##4) ACCQ(p##5) ACCQ(p##6) ACCQ(p##7)

__global__ __launch_bounds__(256) void aggregate_kernel(const char* __restrict__ xsb,
                                                        const int* __restrict__ rowptr,
                                                        const u16* __restrict__ col,
                                                        const float* __restrict__ dis,
                                                        u32* __restrict__ ob, int N){
  const int lane = threadIdx.x & 63;
  const int v = blockIdx.x * 4 + (threadIdx.x >> 6);
  if (v >= N) return;
  const u32 loff = (u32)(lane << 4);

  auto ld = [&](u32 node) -> u32x4 {
    return *(const u32x4*)(xsb + (((size_t)node << 10) + loff));
  };

  float a0, a1, a2, a3, a4, a5, a6, a7;
  {
    u32x4 q = ld((u32)v);  // self loop term
    a0 = bflo(q[0]); a1 = bfhi(q[0]); a2 = bflo(q[1]); a3 = bfhi(q[1]);
    a4 = bflo(q[2]); a5 = bfhi(q[2]); a6 = bflo(q[3]); a7 = bfhi(q[3]);
  }

  const int e0 = rowptr[v];
  const int m  = (rowptr[v + 1] - e0) >> 3;   // >= 1
  const u16* cp = col + e0;

  u32x4 qa0, qa1, qa2, qa3, qa4, qa5, qa6, qa7;
  u32x4 qb0, qb1, qb2, qb3, qb4, qb5, qb6, qb7;

  u16x8 c0 = *(const u16x8*)cp;
  u16x8 c1 = *(const u16x8*)(cp + 8);     // over-read -> sentinel slack
  GATHER8(qa, c0);

  int i = 1;
  for (; i + 1 < m; i += 2){
    c0 = *(const u16x8*)(cp + 8 * (i + 1));
    GATHER8(qb, c1);
    CONS8(qa);
    c1 = *(const u16x8*)(cp + 8 * (i + 2));
    GATHER8(qa, c0);
    CONS8(qb);
  }
  if (i < m){
    GATHER8(qb, c1);
    CONS8(qa);
    CONS8(qb);
  } else {
    CONS8(qa);
  }

  const float dv = dis[v];
  u32x4 r;
  r[0] = ((u32)f2bf(dv * a1) << 16) | f2bf(dv * a0);
  r[1] = ((u32)f2bf(dv * a3) << 16) | f2bf(dv * a2);
  r[2] = ((u32)f2bf(dv * a5) << 16) | f2bf(dv * a4);
  r[3] = ((u32)f2bf(dv * a7) << 16) | f2bf(dv * a6);
  *(u32x4*)(ob + (((size_t)v) << 8) + (lane << 2)) = r;
}

// ---------------- GEMM: 256x256 tile, BK=64, 512 thr (8 waves 2Mx4N), counted-vmcnt pipeline ----
// Deep-pipeline schedule (T3+T4): raw s_barrier + inline-asm s_waitcnt vmcnt(8) so the
// next tile's global_load_lds stay in flight across the barrier (never drain to 0 mid-loop).
// T2 swizzle per rule #21: linear LDS dest + pre-swizzled global src chunk + XOR on ds_read.
// T5 setprio around the 64-MFMA cluster. Dynamic LDS 128 KiB (2 dbuf x (A,B) x 256x64 bf16).

__global__ __launch_bounds__(512) void gemm_kernel(const u16* __restrict__ A,
                                                   const u16* __restrict__ Bt,
                                                   const float* __restrict__ bias,
                                                   const float* __restrict__ dis,
                                                   u16* __restrict__ Cb,
                                                   float* __restrict__ Cf,
                                                   int n_real, int last){
  extern __shared__ u16 smem[];
  u16* const sAb = smem;            // [2][256*64]
  u16* const sBb = smem + 32768;    // [2][256*64]

  // bijective XCD-chunk swizzle (nwg divisible by 8: 392 = 8*49)
  const int cpx = gridDim.x >> 3;
  const int wg  = (blockIdx.x & 7) * cpx + (blockIdx.x >> 3);
  const int bm0 = (wg >> 1) << 8;
  const int bn0 = (wg & 1) << 8;

  const int tid  = threadIdx.x;
  const int lane = tid & 63;
  const int wv   = tid >> 6;        // 0..7
  const int wm   = wv >> 2;         // 0..1 -> 128-row half
  const int wn   = wv & 3;          // 0..3 -> 64-col quarter
  const int lr   = lane & 15, lg = lane >> 4;

  const int r0 = tid >> 3;                      // stage row within 64-row pass
  const int cl = (tid & 7) << 3;                // linear LDS elem offset
  const int cg = ((tid & 7) ^ (r0 & 7)) << 3;   // pre-swizzled global elem offset

  f32x4 acc[8][4] = {};

  auto stage = [&](int bsel, int t){
    const int k0 = t << 6;
    u16* dA = sAb + (bsel << 14);
    u16* dB = sBb + (bsel << 14);
    #pragma unroll
    for (int p = 0; p < 4; ++p){
      const int row = (p << 6) + r0;
      gload_lds16(A  + (((size_t)(bm0 + row)) << 9) + k0 + cg, (void*)&dA[(row << 6) + cl]);
      gload_lds16(Bt + (((size_t)(bn0 + row)) << 9) + k0 + cg, (void*)&dB[(row << 6) + cl]);
    }
  };

  stage(0, 0);   // 8 loads/thread per stage
  stage(1, 1);   // 16 outstanding after prologue

  #pragma unroll
  for (int t = 0; t < 8; ++t){
    const int cur = t & 1;
    // wait tile t landed; tile t+1's 8 loads remain in flight (counted, never 0 mid-loop)
    if (t < 7) asm volatile("s_waitcnt vmcnt(8)" ::: "memory");
    else       asm volatile("s_waitcnt vmcnt(0)" ::: "memory");
    __builtin_amdgcn_s_barrier();
    __builtin_amdgcn_sched_barrier(0);

    const bf16x8* A8 = (const bf16x8*)(sAb + (cur << 14));
    const bf16x8* B8 = (const bf16x8*)(sBb + (cur << 14));
    __builtin_amdgcn_s_setprio(1);
    #pragma unroll
    for (int ks = 0; ks < 2; ++ks){
      const int cswz = ((ks << 2) + lg) ^ (lr & 7);   // read-side swizzled 16B chunk
      bf16x8 bg[4];
      #pragma unroll
      for (int ni = 0; ni < 4; ++ni)
        bg[ni] = B8[(((wn << 6) + (ni << 4) + lr) << 3) + cswz];
      #pragma unroll
      for (int mi = 0; mi < 8; ++mi){
        bf16x8 af = A8[(((wm << 7) + (mi << 4) + lr) << 3) + cswz];
        #pragma unroll
        for (int ni = 0; ni < 4; ++ni)
          acc[mi][ni] = __builtin_amdgcn_mfma_f32_16x16x32_bf16(af, bg[ni], acc[mi][ni], 0, 0, 0);
      }
    }
    __builtin_amdgcn_s_setprio(0);
    __builtin_amdgcn_sched_barrier(0);
    __builtin_amdgcn_s_barrier();      // all waves done reading buf[cur]
    if (t < 6) stage(cur, t + 2);      // refill freed buffer; overlaps next iter's MFMAs
  }

  float bb[4];
  #pragma unroll
  for (int ni = 0; ni < 4; ++ni) bb[ni] = bias[bn0 + (wn << 6) + (ni << 4) + lr];

  // C/D layout: col=lane&15, row=(lane>>4)*4+reg  [m89-verified]
  #pragma unroll
  for (int mi = 0; mi < 8; ++mi){
    const int row0 = bm0 + (wm << 7) + (mi << 4) + (lg << 2);
    const f32x4 dv4 = *(const f32x4*)(dis + row0);   // dis padded; rows>=n_real unused
    #pragma unroll
    for (int ni = 0; ni < 4; ++ni){
      const int c0 = bn0 + (wn << 6) + (ni << 4) + lr;
      #pragma unroll
      for (int r = 0; r < 4; ++r){
        const int row = row0 + r;
        const float val = fmaxf(acc[mi][ni][r] + bb[ni], 0.f);
        if (!last){
          Cb[(((size_t)row) << 9) + c0] = (row < n_real) ? f2bf(dv4[r] * val) : (u16)0;
        } else if (row < n_real){
          Cf[(((size_t)row) << 9) + c0] = val;
        }
      }
    }
  }
}

// ---------------- launch ----------------

extern "C" void kernel_launch(void* const* d_in, const int* in_sizes, int n_in,
                              void* d_out, int out_size, void* d_ws, size_t ws_size,
                              hipStream_t stream) {
  const float* x    = (const float*)d_in[0];
  const int*   ei   = (const int*)d_in[1];   // [2][E] int32: src = ei, dst = ei + E
  const float* W    = (const float*)d_in[2]; // [L][512][512]
  const float* bias = (const float*)d_in[3]; // [L][512]
  float* out = (float*)d_out;

  const int N = in_sizes[0] >> 9;       // 50000
  const int E = in_sizes[1] >> 1;       // 800000
  const int L = in_sizes[3] >> 9;       // 3
  const int MPAD = (N + 255) & ~255;    // 50176 (256-tile bands; > N so row N is a zero pad row)
  const int NB = (N + 1023) / 1024;     // scan blocks (49)

  char* p = (char*)d_ws;
  auto alloc = [&](size_t bytes){ char* q = p; p += (bytes + 255) & ~(size_t)255; return q; };
  u16*   xb       = (u16*)alloc((size_t)MPAD * 512 * 2);
  u16*   aggb     = (u16*)alloc((size_t)MPAD * 512 * 2);
  u16*   wt       = (u16*)alloc((size_t)L * 512 * 512 * 2);
  float* dis      = (float*)alloc((size_t)(MPAD + 4) * 4);  // padded for epilogue f32x4 reads
  int*   rowptr_d = (int*)alloc((size_t)(N + 1) * 4);
  int*   cursor_d = (int*)alloc((size_t)N * 4);
  int*   cnt_d    = (int*)alloc((size_t)N * 4);
  u16*   col      = (u16*)alloc(((size_t)E + 8 * (size_t)N + 64) * 2);
  int*   bsums_d  = (int*)alloc(256 * 4);

  hipFuncSetAttribute((const void*)gemm_kernel,
                      hipFuncAttributeMaxDynamicSharedMemorySize, 131072);

  hipMemsetAsync(cnt_d, 0, (size_t)N * 4, stream);
  // zero pad rows of aggb once per call; agg only writes rows < N
  hipMemsetAsync(aggb + (size_t)N * 512, 0, (size_t)(MPAD - N) * 512 * 2, stream);

  count_deg_kernel<<<(E + 255) / 256, 256, 0, stream>>>(ei + E, E, cnt_d);
  scan1_kernel<<<NB, 1024, 0, stream>>>(cnt_d, N, rowptr_d, bsums_d);
  scan2_kernel<<<1, 256, 0, stream>>>(bsums_d, NB);
  finalize_kernel<<<(N + 255) / 256, 256, 0, stream>>>(rowptr_d, cursor_d, bsums_d, NB, cnt_d, dis, N);
  fill_csr_kernel<<<(E + 255) / 256, 256, 0, stream>>>(ei, ei + E, E, cursor_d, col);
  pad_fill_kernel<<<(N + 255) / 256, 256, 0, stream>>>(rowptr_d, cnt_d, N, col);

  const int ntot = MPAD * 512;
  convert_x_kernel<<<(ntot / 8 + 255) / 256, 256, 0, stream>>>(x, dis, (u32*)xb, N * 512, ntot);
  convert_w_kernel<<<(L * 512 * 512 + 255) / 256, 256, 0, stream>>>(W, wt, L * 512 * 512);

  const int ggrid = (MPAD / 256) * 2;   // 392 = 8*49, divisible by 8
  for (int l = 0; l < L; ++l){
    aggregate_kernel<<<(N + 3) / 4, 256, 0, stream>>>((const char*)xb, rowptr_d, col, dis,
                                                      (u32*)aggb, N);
    gemm_kernel<<<ggrid, 512, 131072, stream>>>(aggb, wt + (size_t)l * 512 * 512,
                                                bias + (size_t)l * 512, dis,
                                                xb, out, N, (l == L - 1) ? 1 : 0);
  }
}